// Round 5
// baseline (178.046 us; speedup 1.0000x reference)
//
#include <hip/hip_runtime.h>
#include <hip/hip_bf16.h>

#define B_ 8
#define S_ 2048
#define F_ 1024
#define DK_ 128
#define M_ (B_*S_)          // 16384
#define LOG2E 1.4426950408889634f

typedef unsigned short u16;
typedef short short8 __attribute__((ext_vector_type(8)));
typedef float f32x4 __attribute__((ext_vector_type(4)));

__device__ __forceinline__ u16 f2bf(float f) {
    unsigned int u = __float_as_uint(f);
    u += 0x7FFFu + ((u >> 16) & 1u);    // round-to-nearest-even
    return (u16)(u >> 16);
}
__device__ __forceinline__ unsigned int pack2(float a, float b) {
    return (unsigned int)f2bf(a) | ((unsigned int)f2bf(b) << 16);
}
__device__ __forceinline__ float fexp2(float x) {
#if __has_builtin(__builtin_amdgcn_exp2f)
    return __builtin_amdgcn_exp2f(x);   // raw v_exp_f32 (2^x)
#else
    return exp2f(x);
#endif
}

// ---------------------------------------------------------------------------
// Kernel 1: W [1024][128] fp32 -> WT [3][128][1024] bf16 (transposed),
// 1/sqrt(DK) folded into w_q.
// ---------------------------------------------------------------------------
__global__ __launch_bounds__(256) void prep_wt(const float* __restrict__ wq,
                                               const float* __restrict__ wk,
                                               const float* __restrict__ wv,
                                               u16* __restrict__ WT) {
    int id = blockIdx.x * 256 + threadIdx.x;
    if (id >= 3 * DK_ * F_) return;
    int m   = id / (DK_ * F_);
    int rem = id - m * (DK_ * F_);
    int c   = rem / F_;
    int k   = rem - c * F_;
    const float* w = (m == 0) ? wq : (m == 1) ? wk : wv;
    float v = w[k * DK_ + c];
    if (m == 0) v *= 0.08838834764831845f;   // 1/sqrt(128)
    WT[id] = f2bf(v);
}

// ---------------------------------------------------------------------------
// Kernel 2: projection GEMM.  X [16384][1024] fp32  x  W -> bf16 outputs.
// mode 0: qp [16384][128], mode 1: kp [16384][128], mode 2: vpT [128][16384]
// Block 256 thr (4 waves), tile 64 rows x 128 cols (16 rows/wave), BK=32.
// 768 blocks total -> 3 blocks/CU, 12 waves/CU.
// ---------------------------------------------------------------------------
__global__ __launch_bounds__(256, 3) void proj(const float* __restrict__ xq,
                                               const float* __restrict__ xk,
                                               const float* __restrict__ xv,
                                               const u16* __restrict__ WT,
                                               u16* __restrict__ qp,
                                               u16* __restrict__ kp,
                                               u16* __restrict__ vpT) {
    const int mode = blockIdx.y;
    const float* X = (mode == 0) ? xq : (mode == 1) ? xk : xv;
    const u16*   W = WT + mode * (DK_ * F_);

    __shared__ u16 a_lds[64][40];    // row stride 80B (16B-aligned), bank-spread
    __shared__ u16 w_lds[128][40];

    const int t    = threadIdx.x;
    const int lane = t & 63;
    const int wv_  = t >> 6;
    const int l15  = lane & 15, l4 = lane >> 4;
    const int row0 = blockIdx.x * 64;

    f32x4 acc[8];
#pragma unroll
    for (int j = 0; j < 8; ++j) acc[j] = f32x4{0.f, 0.f, 0.f, 0.f};

    for (int k0 = 0; k0 < F_; k0 += 32) {
        // stage A tile 64x32 (fp32 -> bf16): thread -> row t>>2, k-chunk (t&3)*8
        {
            int r = t >> 2, kk = (t & 3) * 8;
            const float4* src = (const float4*)(X + (size_t)(row0 + r) * F_ + k0 + kk);
            float4 f0 = src[0], f1 = src[1];
            int4 o0;
            o0.x = pack2(f0.x, f0.y); o0.y = pack2(f0.z, f0.w);
            o0.z = pack2(f1.x, f1.y); o0.w = pack2(f1.z, f1.w);
            *(int4*)&a_lds[r][kk] = o0;
        }
        // stage W^T tile 128x32 (already bf16)
        {
            int c = t >> 1, kk = (t & 1) * 16;
            const int4* src = (const int4*)(W + (size_t)c * F_ + k0 + kk);
            *(int4*)&w_lds[c][kk]     = src[0];
            *(int4*)&w_lds[c][kk + 8] = src[1];
        }
        __syncthreads();

        short8 af = *(const short8*)&a_lds[wv_ * 16 + l15][l4 * 8];
        short8 bf[8];
#pragma unroll
        for (int ct = 0; ct < 8; ++ct)
            bf[ct] = *(const short8*)&w_lds[ct * 16 + l15][l4 * 8];

        if (mode < 2) {
#pragma unroll
            for (int ct = 0; ct < 8; ++ct)
                acc[ct] = __builtin_amdgcn_mfma_f32_16x16x32_bf16(af, bf[ct], acc[ct], 0, 0, 0);
        } else {
#pragma unroll
            for (int ct = 0; ct < 8; ++ct)
                acc[ct] = __builtin_amdgcn_mfma_f32_16x16x32_bf16(bf[ct], af, acc[ct], 0, 0, 0);
        }
        __syncthreads();
    }

    if (mode < 2) {
        u16* OUT = (mode == 0) ? qp : kp;
#pragma unroll
        for (int ct = 0; ct < 8; ++ct)
#pragma unroll
            for (int r = 0; r < 4; ++r) {
                int row = row0 + wv_ * 16 + l4 * 4 + r;
                int col = ct * 16 + l15;
                OUT[(size_t)row * DK_ + col] = f2bf(acc[ct][r]);
            }
    } else {
        // swapped operands: D[row=n][col=m] -> store transposed vpT[n][m]
#pragma unroll
        for (int ct = 0; ct < 8; ++ct)
#pragma unroll
            for (int r = 0; r < 4; ++r) {
                int n = ct * 16 + l4 * 4 + r;
                int m = row0 + wv_ * 16 + l15;
                vpT[(size_t)n * M_ + m] = f2bf(acc[ct][r]);
            }
    }
}

// ---------------------------------------------------------------------------
// Kernel 3: flash attention, in-block KV-split x8, register-resident K/V
// tiles with software prefetch (ILP over TLP).
// Grid 512: b = blk&7 (XCD-pins batch KV in one L2), qi = blk>>3 -> 32 q rows.
// Block 512 thr = 8 waves; wave w owns KV slice [w*256, w*256+256).
// __launch_bounds__(512, 1): 256-VGPR cap -> whole K tile (64 VGPR) + V tile
// (64 VGPR) live at once; V loads issued before softmax (hidden under it),
// next K tile prefetched before PV. Round-4's 112-VGPR squeeze serialized
// ~32 L2 loads/iter at ~300 cyc each = the 110 us.
// ---------------------------------------------------------------------------
union attn_lds_t {
    struct { __align__(16) unsigned char p[8][4096]; } s1;     // loop phase: P slots (32 KB)
    struct { float oA[32][132]; float oB[32][132]; } s2;       // epilogue: combine (33.8 KB)
};

__global__ __launch_bounds__(512, 1) void attn(const u16* __restrict__ qp,
                                               const u16* __restrict__ kp,
                                               const u16* __restrict__ vpT,
                                               float* __restrict__ out) {
    __shared__ attn_lds_t u;
    __shared__ float m_lds[8][32], l_lds[8][32], gm_lds[32], gl_lds[32];

    const int t    = threadIdx.x;
    const int lane = t & 63;
    const int wv_  = t >> 6;                 // 0..7
    const int l15  = lane & 15, l4 = lane >> 4;

    const int b  = blockIdx.x & 7;
    const int qi = blockIdx.x >> 3;
    const int qbase = b * S_ + qi * 32;

    // Q fragments (32 rows, scale folded into w_q; same for all 8 waves)
    short8 qf[2][4];
#pragma unroll
    for (int rt = 0; rt < 2; ++rt)
#pragma unroll
        for (int kc = 0; kc < 4; ++kc)
            qf[rt][kc] = *(const short8*)(qp + (size_t)(qbase + rt * 16 + l15) * DK_
                                             + kc * 32 + l4 * 8);

    f32x4 o[2][8];
#pragma unroll
    for (int i = 0; i < 2; ++i)
#pragma unroll
        for (int j = 0; j < 8; ++j) o[i][j] = f32x4{0.f, 0.f, 0.f, 0.f};
    float mrun[2][4], lrun[2][4];
#pragma unroll
    for (int i = 0; i < 2; ++i)
#pragma unroll
        for (int r = 0; r < 4; ++r) { mrun[i][r] = -3.0e38f; lrun[i][r] = 0.f; }

    unsigned char* pb = &u.s1.p[wv_][0];
    const int kv_lo = b * S_ + wv_ * 256;    // absolute row base of this wave's slice

    short8 kf[4][4];   // current K tile, 64 VGPR
    short8 vf[2][8];   // current V tile, 64 VGPR

    // preload K tile 0
#pragma unroll
    for (int ct = 0; ct < 4; ++ct)
#pragma unroll
        for (int kc = 0; kc < 4; ++kc)
            kf[ct][kc] = *(const short8*)(kp + (size_t)(kv_lo + ct * 16 + l15) * DK_
                                             + kc * 32 + l4 * 8);

#pragma unroll
    for (int kt = 0; kt < 4; ++kt) {
        const int kv0 = kv_lo + kt * 64;

        // ---- QK^T: s[q 32][kv 64] from register-resident K tile
        f32x4 s[2][4];
#pragma unroll
        for (int i = 0; i < 2; ++i)
#pragma unroll
            for (int j = 0; j < 4; ++j) s[i][j] = f32x4{0.f, 0.f, 0.f, 0.f};
#pragma unroll
        for (int ct = 0; ct < 4; ++ct)
#pragma unroll
            for (int kc = 0; kc < 4; ++kc)
#pragma unroll
                for (int rt = 0; rt < 2; ++rt)
                    s[rt][ct] = __builtin_amdgcn_mfma_f32_16x16x32_bf16(
                        qf[rt][kc], kf[ct][kc], s[rt][ct], 0, 0, 0);

        // ---- issue V loads NOW; they complete under the softmax below
#pragma unroll
        for (int kc2 = 0; kc2 < 2; ++kc2)
#pragma unroll
            for (int ct = 0; ct < 8; ++ct)
                vf[kc2][ct] = *(const short8*)(vpT + (size_t)(ct * 16 + l15) * M_
                                                   + kv0 + kc2 * 32 + l4 * 8);

        // ---- online softmax (+ P -> wave-private LDS as bf16)
#pragma unroll
        for (int rt = 0; rt < 2; ++rt) {
            float fs[4], sum[4];
#pragma unroll
            for (int r = 0; r < 4; ++r) {
                float v0 = fmaxf(fmaxf(s[rt][0][r], s[rt][1][r]),
                                 fmaxf(s[rt][2][r], s[rt][3][r]));
#pragma unroll
                for (int msk = 1; msk < 16; msk <<= 1)
                    v0 = fmaxf(v0, __shfl_xor(v0, msk, 64));
                float mn = fmaxf(mrun[rt][r], v0);
                fs[r] = fexp2((mrun[rt][r] - mn) * LOG2E);
                mrun[rt][r] = mn;
                sum[r] = 0.f;
            }
#pragma unroll
            for (int ct = 0; ct < 4; ++ct)
#pragma unroll
                for (int r = 0; r < 4; ++r) {
                    float p = fexp2((s[rt][ct][r] - mrun[rt][r]) * LOG2E);
                    sum[r] += p;
                    int prow = rt * 16 + l4 * 4 + r;
                    int pbyte = (prow * 128 + (ct * 16 + l15) * 2) ^ ((prow & 7) << 4);
                    *(u16*)(pb + pbyte) = f2bf(p);
                }
#pragma unroll
            for (int r = 0; r < 4; ++r) {
#pragma unroll
                for (int msk = 1; msk < 16; msk <<= 1)
                    sum[r] += __shfl_xor(sum[r], msk, 64);
                lrun[rt][r] = lrun[rt][r] * fs[r] + sum[r];
            }
#pragma unroll
            for (int ct = 0; ct < 8; ++ct)
#pragma unroll
                for (int r = 0; r < 4; ++r) o[rt][ct][r] *= fs[r];
        }

        // ---- prefetch next K tile (overlaps PV below + next QK issue)
        if (kt < 3) {
#pragma unroll
            for (int ct = 0; ct < 4; ++ct)
#pragma unroll
                for (int kc = 0; kc < 4; ++kc)
                    kf[ct][kc] = *(const short8*)(kp + (size_t)(kv0 + 64 + ct * 16 + l15) * DK_
                                                     + kc * 32 + l4 * 8);
        }

        // ---- PV: o[q 32][d 128] += P[q][kv] * V[kv][d] from register V tile
#pragma unroll
        for (int kc2 = 0; kc2 < 2; ++kc2) {
            short8 pf[2];
#pragma unroll
            for (int rt = 0; rt < 2; ++rt) {
                int prow = rt * 16 + l15;
                pf[rt] = *(const short8*)(pb + ((prow * 128 + kc2 * 64 + l4 * 16)
                                                ^ ((prow & 7) << 4)));
            }
#pragma unroll
            for (int ct = 0; ct < 8; ++ct)
#pragma unroll
                for (int rt = 0; rt < 2; ++rt)
                    o[rt][ct] = __builtin_amdgcn_mfma_f32_16x16x32_bf16(
                        pf[rt], vf[kc2][ct], o[rt][ct], 0, 0, 0);
        }
    }

    // ---- cross-wave combine (8 partials) ----
    if (l15 == 0) {
#pragma unroll
        for (int rt = 0; rt < 2; ++rt)
#pragma unroll
            for (int r = 0; r < 4; ++r) {
                m_lds[wv_][rt * 16 + l4 * 4 + r] = mrun[rt][r];
                l_lds[wv_][rt * 16 + l4 * 4 + r] = lrun[rt][r];
            }
    }
    __syncthreads();     // also fences last P read before union reuse
    if (t < 32) {
        float gm = -3.0e38f;
#pragma unroll
        for (int w = 0; w < 8; ++w) gm = fmaxf(gm, m_lds[w][t]);
        float gl = 0.f;
#pragma unroll
        for (int w = 0; w < 8; ++w)
            gl += l_lds[w][t] * fexp2((m_lds[w][t] - gm) * LOG2E);
        gm_lds[t] = gm;
        gl_lds[t] = gl;
    }
    __syncthreads();

    float sc[2][4];
#pragma unroll
    for (int rt = 0; rt < 2; ++rt)
#pragma unroll
        for (int r = 0; r < 4; ++r) {
            int row = rt * 16 + l4 * 4 + r;
            sc[rt][r] = fexp2((mrun[rt][r] - gm_lds[row]) * LOG2E);
        }

    float* slot = (wv_ & 1) ? &u.s2.oB[0][0] : &u.s2.oA[0][0];
    const int rnd = wv_ >> 1;                 // 0..3
    for (int rr = 0; rr < 4; ++rr) {
        if (rnd == rr) {
            if (rr == 0) {
#pragma unroll
                for (int rt = 0; rt < 2; ++rt)
#pragma unroll
                    for (int ct = 0; ct < 8; ++ct)
#pragma unroll
                        for (int r = 0; r < 4; ++r) {
                            int row = rt * 16 + l4 * 4 + r;
                            slot[row * 132 + ct * 16 + l15] = o[rt][ct][r] * sc[rt][r];
                        }
            } else {
#pragma unroll
                for (int rt = 0; rt < 2; ++rt)
#pragma unroll
                    for (int ct = 0; ct < 8; ++ct)
#pragma unroll
                        for (int r = 0; r < 4; ++r) {
                            int row = rt * 16 + l4 * 4 + r;
                            slot[row * 132 + ct * 16 + l15] += o[rt][ct][r] * sc[rt][r];
                        }
            }
        }
        __syncthreads();
    }

    // ---- final: (oA+oB)/gl -> out (fp32); thread t: row t>>4, cols (t&15)*8..+8
    {
        int row = t >> 4, c0 = (t & 15) * 8;
        float inv = 1.0f / gl_lds[row];
        float* dst = out + (size_t)(qbase + row) * DK_ + c0;
#pragma unroll
        for (int j = 0; j < 8; j += 4) {
            float4 v;
            v.x = (u.s2.oA[row][c0 + j]     + u.s2.oB[row][c0 + j])     * inv;
            v.y = (u.s2.oA[row][c0 + j + 1] + u.s2.oB[row][c0 + j + 1]) * inv;
            v.z = (u.s2.oA[row][c0 + j + 2] + u.s2.oB[row][c0 + j + 2]) * inv;
            v.w = (u.s2.oA[row][c0 + j + 3] + u.s2.oB[row][c0 + j + 3]) * inv;
            *(float4*)(dst + j) = v;
        }
    }
}

// ---------------------------------------------------------------------------
extern "C" void kernel_launch(void* const* d_in, const int* in_sizes, int n_in,
                              void* d_out, int out_size, void* d_ws, size_t ws_size,
                              hipStream_t stream) {
    const float* q  = (const float*)d_in[0];
    const float* k  = (const float*)d_in[1];
    const float* v  = (const float*)d_in[2];
    const float* wq = (const float*)d_in[3];
    const float* wk = (const float*)d_in[4];
    const float* wv = (const float*)d_in[5];
    float* out = (float*)d_out;

    char* ws = (char*)d_ws;
    u16* WT  = (u16*)ws;                                   // 3*128*1024*2 = 786432 B
    u16* qp  = (u16*)(ws + 786432);                        // 4 MB
    u16* kp  = (u16*)(ws + 786432 + 4194304);              // 4 MB
    u16* vpT = (u16*)(ws + 786432 + 2 * 4194304);          // 4 MB  (total ~12.75 MB)

    prep_wt<<<dim3(1536), dim3(256), 0, stream>>>(wq, wk, wv, WT);
    proj<<<dim3(256, 3), dim3(256), 0, stream>>>(q, k, v, WT, qp, kp, vpT);
    attn<<<dim3(512), dim3(512), 0, stream>>>(qp, kp, vpT, out);
}

// Round 6
// 110.839 us; speedup vs baseline: 1.6063x; 1.6063x over previous
//
#include <hip/hip_runtime.h>
#include <hip/hip_bf16.h>

#define B_ 8
#define S_ 2048
#define F_ 1024
#define DK_ 128
#define M_ (B_*S_)          // 16384

typedef unsigned short u16;
typedef short short8 __attribute__((ext_vector_type(8)));
typedef float f32x4 __attribute__((ext_vector_type(4)));
typedef float f32x16 __attribute__((ext_vector_type(16)));

__device__ __forceinline__ u16 f2bf(float f) {
    unsigned int u = __float_as_uint(f);
    u += 0x7FFFu + ((u >> 16) & 1u);    // round-to-nearest-even
    return (u16)(u >> 16);
}
__device__ __forceinline__ unsigned int pack2(float a, float b) {
    return (unsigned int)f2bf(a) | ((unsigned int)f2bf(b) << 16);
}
__device__ __forceinline__ float fexp2(float x) {
#if __has_builtin(__builtin_amdgcn_exp2f)
    return __builtin_amdgcn_exp2f(x);   // raw v_exp_f32 (2^x)
#else
    return exp2f(x);
#endif
}
__device__ __forceinline__ unsigned int cvt_pk_bf16(float lo, float hi) {
    unsigned int r;
    asm volatile("v_cvt_pk_bf16_f32 %0, %1, %2" : "=v"(r) : "v"(lo), "v"(hi));
    return r;
}

// ---------------------------------------------------------------------------
// Kernel 1: W [1024][128] fp32 -> WT [3][128][1024] bf16 (transposed).
// w_q gets (1/sqrt(128)) * log2(e) folded in, so softmax uses raw exp2.
// ---------------------------------------------------------------------------
__global__ __launch_bounds__(256) void prep_wt(const float* __restrict__ wq,
                                               const float* __restrict__ wk,
                                               const float* __restrict__ wv,
                                               u16* __restrict__ WT) {
    int id = blockIdx.x * 256 + threadIdx.x;
    if (id >= 3 * DK_ * F_) return;
    int m   = id / (DK_ * F_);
    int rem = id - m * (DK_ * F_);
    int c   = rem / F_;
    int k   = rem - c * F_;
    const float* w = (m == 0) ? wq : (m == 1) ? wk : wv;
    float v = w[k * DK_ + c];
    if (m == 0) v *= 0.12751741951f;   // (1/sqrt(128)) * log2(e)
    WT[id] = f2bf(v);
}

// ---------------------------------------------------------------------------
// Kernel 2: projection GEMM.  X [16384][1024] fp32  x  W -> bf16 outputs.
// mode 0: qp [16384][128], mode 1: kp [16384][128], mode 2: vpT [128][16384]
// Block 256 thr (4 waves), tile 64 rows x 128 cols (16 rows/wave), BK=32.
// ---------------------------------------------------------------------------
__global__ __launch_bounds__(256, 3) void proj(const float* __restrict__ xq,
                                               const float* __restrict__ xk,
                                               const float* __restrict__ xv,
                                               const u16* __restrict__ WT,
                                               u16* __restrict__ qp,
                                               u16* __restrict__ kp,
                                               u16* __restrict__ vpT) {
    const int mode = blockIdx.y;
    const float* X = (mode == 0) ? xq : (mode == 1) ? xk : xv;
    const u16*   W = WT + mode * (DK_ * F_);

    __shared__ u16 a_lds[64][40];    // row stride 80B (16B-aligned), bank-spread
    __shared__ u16 w_lds[128][40];

    const int t    = threadIdx.x;
    const int lane = t & 63;
    const int wv_  = t >> 6;
    const int l15  = lane & 15, l4 = lane >> 4;
    const int row0 = blockIdx.x * 64;

    f32x4 acc[8];
#pragma unroll
    for (int j = 0; j < 8; ++j) acc[j] = f32x4{0.f, 0.f, 0.f, 0.f};

    for (int k0 = 0; k0 < F_; k0 += 32) {
        {
            int r = t >> 2, kk = (t & 3) * 8;
            const float4* src = (const float4*)(X + (size_t)(row0 + r) * F_ + k0 + kk);
            float4 f0 = src[0], f1 = src[1];
            int4 o0;
            o0.x = pack2(f0.x, f0.y); o0.y = pack2(f0.z, f0.w);
            o0.z = pack2(f1.x, f1.y); o0.w = pack2(f1.z, f1.w);
            *(int4*)&a_lds[r][kk] = o0;
        }
        {
            int c = t >> 1, kk = (t & 1) * 16;
            const int4* src = (const int4*)(W + (size_t)c * F_ + k0 + kk);
            *(int4*)&w_lds[c][kk]     = src[0];
            *(int4*)&w_lds[c][kk + 8] = src[1];
        }
        __syncthreads();

        short8 af = *(const short8*)&a_lds[wv_ * 16 + l15][l4 * 8];
        short8 bf[8];
#pragma unroll
        for (int ct = 0; ct < 8; ++ct)
            bf[ct] = *(const short8*)&w_lds[ct * 16 + l15][l4 * 8];

        if (mode < 2) {
#pragma unroll
            for (int ct = 0; ct < 8; ++ct)
                acc[ct] = __builtin_amdgcn_mfma_f32_16x16x32_bf16(af, bf[ct], acc[ct], 0, 0, 0);
        } else {
#pragma unroll
            for (int ct = 0; ct < 8; ++ct)
                acc[ct] = __builtin_amdgcn_mfma_f32_16x16x32_bf16(bf[ct], af, acc[ct], 0, 0, 0);
        }
        __syncthreads();
    }

    if (mode < 2) {
        u16* OUT = (mode == 0) ? qp : kp;
#pragma unroll
        for (int ct = 0; ct < 8; ++ct)
#pragma unroll
            for (int r = 0; r < 4; ++r) {
                int row = row0 + wv_ * 16 + l4 * 4 + r;
                int col = ct * 16 + l15;
                OUT[(size_t)row * DK_ + col] = f2bf(acc[ct][r]);
            }
    } else {
#pragma unroll
        for (int ct = 0; ct < 8; ++ct)
#pragma unroll
            for (int r = 0; r < 4; ++r) {
                int n = ct * 16 + l4 * 4 + r;
                int m = row0 + wv_ * 16 + l15;
                vpT[(size_t)n * M_ + m] = f2bf(acc[ct][r]);
            }
    }
}

// ---------------------------------------------------------------------------
// Kernel 3: flash attention, swapped-operand 32x32x16 MFMA structure.
// QK^T computed as mfma(K, Q) -> S^T[kv][q]: each lane owns ONE q (q=lane&31),
// so softmax m/l are per-lane SCALARS, row-reduce = 15 in-reg max + 1 shfl,
// P stays in registers (cvt_pk_bf16 + shfl_xor(32) + cndmask rebuilds the
// PV B-fragment), PV computed as mfma(V^T, P^T) -> O^T[d][q].
// No LDS in the main loop; defer-max (THR=8 in log2 units) skips O-rescale.
// Grid 512 (b=blk&7 XCD-pins KV), block 512 thr = 8 waves, wave w owns
// kv slice [w*256, (w+1)*256) in 8 tiles of 32.  LDS epilogue combine.
// ---------------------------------------------------------------------------
__global__ __launch_bounds__(512, 2) void attn(const u16* __restrict__ qp,
                                               const u16* __restrict__ kp,
                                               const u16* __restrict__ vpT,
                                               float* __restrict__ out) {
    __shared__ float oA[128 * 33], oB[128 * 33];
    __shared__ float m_lds[8][32], l_lds[8][32], gm_lds[32], gl_lds[32];

    const int t    = threadIdx.x;
    const int lane = t & 63;
    const int wv_  = t >> 6;                 // 0..7
    const int r31  = lane & 31;              // q index (as B-col) / kv,d row (as A-row)
    const int hi   = lane >> 5;              // which 8-wide k-group this lane feeds

    const int b  = blockIdx.x & 7;
    const int qi = blockIdx.x >> 3;
    const int qbase = b * S_ + qi * 32;

    // Q as persistent B-fragments: qf[c] = Q[q=r31][d = c*16 + hi*8 + 0..7]
    short8 qf[8];
#pragma unroll
    for (int c = 0; c < 8; ++c)
        qf[c] = *(const short8*)(qp + (size_t)(qbase + r31) * DK_ + c * 16 + hi * 8);

    f32x16 o4[4];
#pragma unroll
    for (int ct = 0; ct < 4; ++ct)
#pragma unroll
        for (int i = 0; i < 16; ++i) o4[ct][i] = 0.f;
    float mrun = -1.0e30f, lrun = 0.f;

    const int kv_lo = b * S_ + wv_ * 256;

    for (int kt = 0; kt < 8; ++kt) {
        const int kv0 = kv_lo + kt * 32;

        // ---- load K tile (A-frags: row=kv=r31, k=d) and V^T tile (row=d, k=kv)
        short8 kf[8];
#pragma unroll
        for (int c = 0; c < 8; ++c)
            kf[c] = *(const short8*)(kp + (size_t)(kv0 + r31) * DK_ + c * 16 + hi * 8);
        short8 vf[4][2];
#pragma unroll
        for (int ct = 0; ct < 4; ++ct)
#pragma unroll
            for (int ch = 0; ch < 2; ++ch)
                vf[ct][ch] = *(const short8*)(vpT + (size_t)(ct * 32 + r31) * M_
                                                  + kv0 + ch * 16 + hi * 8);

        // ---- QK^T: st[reg] = S^T[kv = (reg&3)+8*(reg>>2)+4*hi][q = r31]
        f32x16 st;
#pragma unroll
        for (int i = 0; i < 16; ++i) st[i] = 0.f;
#pragma unroll
        for (int c = 0; c < 8; ++c)
            st = __builtin_amdgcn_mfma_f32_32x32x16_bf16(kf[c], qf[c], st, 0, 0, 0);

        // ---- per-lane softmax (scores already in log2 units)
        float tm = st[0];
#pragma unroll
        for (int i = 1; i < 16; ++i) tm = fmaxf(tm, st[i]);
        tm = fmaxf(tm, __shfl_xor(tm, 32, 64));
        if (__any(tm > mrun + 8.0f)) {       // defer-max: rescale only on real growth
            float mn = fmaxf(mrun, tm);
            float fs = fexp2(mrun - mn);
            mrun = mn;
            lrun *= fs;
#pragma unroll
            for (int ct = 0; ct < 4; ++ct)
#pragma unroll
                for (int i = 0; i < 16; ++i) o4[ct][i] *= fs;
        }
        float p[16];
        float sum = 0.f;
#pragma unroll
        for (int i = 0; i < 16; ++i) { p[i] = fexp2(st[i] - mrun); sum += p[i]; }
        sum += __shfl_xor(sum, 32, 64);
        lrun += sum;

        // ---- P -> bf16 B-fragments in-register (no LDS)
        // lane's p[i] holds kv = (i&3)+8*(i>>2)+4*hi; B-frag needs
        // kv = ch*16 + hi*8 + j for j=0..7.
        short8 bp[2];
#pragma unroll
        for (int ch = 0; ch < 2; ++ch) {
            unsigned int wa = cvt_pk_bf16(p[ch * 8 + 0], p[ch * 8 + 1]);
            unsigned int wb = cvt_pk_bf16(p[ch * 8 + 2], p[ch * 8 + 3]);
            unsigned int wc = cvt_pk_bf16(p[ch * 8 + 4], p[ch * 8 + 5]);
            unsigned int wd = cvt_pk_bf16(p[ch * 8 + 6], p[ch * 8 + 7]);
            unsigned int xa = (unsigned int)__shfl_xor((int)wa, 32, 64);
            unsigned int xb = (unsigned int)__shfl_xor((int)wb, 32, 64);
            unsigned int xc = (unsigned int)__shfl_xor((int)wc, 32, 64);
            unsigned int xd = (unsigned int)__shfl_xor((int)wd, 32, 64);
            int4 w;
            w.x = (int)(hi ? xc : wa);   // elements 0,1
            w.y = (int)(hi ? xd : wb);   // elements 2,3
            w.z = (int)(hi ? wc : xa);   // elements 4,5
            w.w = (int)(hi ? wd : xb);   // elements 6,7
            bp[ch] = *(short8*)&w;
        }

        // ---- PV: O^T[d][q] += V^T x P^T
#pragma unroll
        for (int ct = 0; ct < 4; ++ct) {
            o4[ct] = __builtin_amdgcn_mfma_f32_32x32x16_bf16(vf[ct][0], bp[0], o4[ct], 0, 0, 0);
            o4[ct] = __builtin_amdgcn_mfma_f32_32x32x16_bf16(vf[ct][1], bp[1], o4[ct], 0, 0, 0);
        }
    }

    // ---- cross-wave combine (8 partials over kv) ----
    if (lane < 32) {                         // hi==0 half; both halves agree on m/l
        m_lds[wv_][r31] = mrun;
        l_lds[wv_][r31] = lrun;
    }
    __syncthreads();
    if (t < 32) {
        float gm = -1.0e30f;
#pragma unroll
        for (int w = 0; w < 8; ++w) gm = fmaxf(gm, m_lds[w][t]);
        float gl = 0.f;
#pragma unroll
        for (int w = 0; w < 8; ++w)
            gl += l_lds[w][t] * fexp2(m_lds[w][t] - gm);
        gm_lds[t] = gm;
        gl_lds[t] = gl;
    }
    __syncthreads();

    const float sc = fexp2(mrun - gm_lds[r31]);
    float* slot = (wv_ & 1) ? oB : oA;
    const int rnd = wv_ >> 1;                 // 0..3
    for (int rr = 0; rr < 4; ++rr) {
        if (rnd == rr) {
            if (rr == 0) {
#pragma unroll
                for (int ct = 0; ct < 4; ++ct)
#pragma unroll
                    for (int i = 0; i < 16; ++i) {
                        int d = ct * 32 + (i & 3) + 8 * (i >> 2) + 4 * hi;
                        slot[d * 33 + r31] = o4[ct][i] * sc;
                    }
            } else {
#pragma unroll
                for (int ct = 0; ct < 4; ++ct)
#pragma unroll
                    for (int i = 0; i < 16; ++i) {
                        int d = ct * 32 + (i & 3) + 8 * (i >> 2) + 4 * hi;
                        slot[d * 33 + r31] += o4[ct][i] * sc;
                    }
            }
        }
        __syncthreads();
    }

    // ---- final: (oA+oB)/gl, transpose O^T -> out[q][d]
    {
        int qq = t & 31, d0 = (t >> 5) * 8;
        float inv = 1.0f / gl_lds[qq];
        float* dst = out + (size_t)(qbase + qq) * DK_ + d0;
        float4 v0, v1;
        v0.x = (oA[(d0 + 0) * 33 + qq] + oB[(d0 + 0) * 33 + qq]) * inv;
        v0.y = (oA[(d0 + 1) * 33 + qq] + oB[(d0 + 1) * 33 + qq]) * inv;
        v0.z = (oA[(d0 + 2) * 33 + qq] + oB[(d0 + 2) * 33 + qq]) * inv;
        v0.w = (oA[(d0 + 3) * 33 + qq] + oB[(d0 + 3) * 33 + qq]) * inv;
        v1.x = (oA[(d0 + 4) * 33 + qq] + oB[(d0 + 4) * 33 + qq]) * inv;
        v1.y = (oA[(d0 + 5) * 33 + qq] + oB[(d0 + 5) * 33 + qq]) * inv;
        v1.z = (oA[(d0 + 6) * 33 + qq] + oB[(d0 + 6) * 33 + qq]) * inv;
        v1.w = (oA[(d0 + 7) * 33 + qq] + oB[(d0 + 7) * 33 + qq]) * inv;
        *(float4*)(dst)     = v0;
        *(float4*)(dst + 4) = v1;
    }
}

// ---------------------------------------------------------------------------
extern "C" void kernel_launch(void* const* d_in, const int* in_sizes, int n_in,
                              void* d_out, int out_size, void* d_ws, size_t ws_size,
                              hipStream_t stream) {
    const float* q  = (const float*)d_in[0];
    const float* k  = (const float*)d_in[1];
    const float* v  = (const float*)d_in[2];
    const float* wq = (const float*)d_in[3];
    const float* wk = (const float*)d_in[4];
    const float* wv = (const float*)d_in[5];
    float* out = (float*)d_out;

    char* ws = (char*)d_ws;
    u16* WT  = (u16*)ws;                                   // 786432 B
    u16* qp  = (u16*)(ws + 786432);                        // 4 MB
    u16* kp  = (u16*)(ws + 786432 + 4194304);              // 4 MB
    u16* vpT = (u16*)(ws + 786432 + 2 * 4194304);          // 4 MB

    prep_wt<<<dim3(1536), dim3(256), 0, stream>>>(wq, wk, wv, WT);
    proj<<<dim3(256, 3), dim3(256), 0, stream>>>(q, k, v, WT, qp, kp, vpT);
    attn<<<dim3(512), dim3(512), 0, stream>>>(qp, kp, vpT, out);
}